// Round 9
// baseline (459.453 us; speedup 1.0000x reference)
//
#include <hip/hip_runtime.h>
#include <hip/hip_cooperative_groups.h>
#include <float.h>
#include <stdint.h>

namespace cg = cooperative_groups;

#define B_  2
#define S_  2048
#define N_  1024
#define H_  1024
#define NH_ 16
#define K_  1024

typedef __attribute__((ext_vector_type(8))) short bf16x8;
typedef __attribute__((ext_vector_type(4))) float f32x4;

typedef __attribute__((address_space(3))) uint32_t lds_u32;
typedef __attribute__((address_space(1))) uint32_t glb_u32;

// async global->LDS, 16B per lane; LDS dest = wave-uniform base + lane*16
__device__ __forceinline__ void gload16(void* l, const void* g) {
    __builtin_amdgcn_global_load_lds((const glb_u32*)g, (lds_u32*)l, 16, 0, 0);
}

// round-to-nearest-even fp32 -> bf16 bits
__device__ __forceinline__ ushort f2bf(float f) {
    uint32_t u = __float_as_uint(f);
    u = (u + 0x7fffu + ((u >> 16) & 1u)) >> 16;
    return (ushort)u;
}

#if __has_builtin(__builtin_amdgcn_cvt_pk_bf16_f32)
typedef __attribute__((ext_vector_type(2))) __bf16 bfp2;
__device__ __forceinline__ uint pk2(float a, float b) {
    bfp2 v = __builtin_amdgcn_cvt_pk_bf16_f32(a, b);
    return __builtin_bit_cast(uint, v);
}
#else
__device__ __forceinline__ uint pk2(float a, float b) {
    return (uint)f2bf(a) | ((uint)f2bf(b) << 16);
}
#endif

__device__ __forceinline__ float fexp2(float x) {
#if __has_builtin(__builtin_amdgcn_exp2f)
    return __builtin_amdgcn_exp2f(x);
#else
    return exp2f(x);
#endif
}

#define SC2 0.180336880f   /* (1/sqrt(64)) * log2(e) — folded into Q proj */

// ===========================================================================
// Cooperative mega-kernel: 256 WGs x 512 thr (1 WG/CU guaranteed — any
// compilable kernel satisfies cooperative co-residency). 2 work units per WG
// per phase. grid.sync() between phases; writer-side __threadfence() (agent
// release -> L2 writeback) gives cross-XCD visibility; no phase reads an
// address its CU touched in an earlier phase (no stale-L1 hazard). No buffer
// aliasing across phases.
// ===========================================================================
__global__ __launch_bounds__(512, 2) void mega(
        const float* __restrict__ tqF, const float* __restrict__ kvF,
        const float* __restrict__ wqF, const float* __restrict__ wkF,
        const float* __restrict__ wvF, const float* __restrict__ woF,
        const int* __restrict__ ends, ushort* __restrict__ ws,
        float* __restrict__ out)
{
    __shared__ __align__(16) ushort smem[25856];   // 51.7 KB max over phases
    cg::grid_group grid = cg::this_grid();

    // ws regions (ushort units)
    ushort* qx  = ws;                       // 4M
    ushort* kvx = ws + 4194304;             // 2M
    ushort* wq  = ws + 6291456;             // 1M
    ushort* wk  = ws + 7340032;             // 1M
    ushort* wv  = ws + 8388608;             // 1M
    ushort* wo  = ws + 9437184;             // 1M
    ushort* Qp  = ws + 10485760;            // 4M
    ushort* Kp  = ws + 14680064;            // 2M
    ushort* VtG = ws + 16777216;            // 2M
    float*  VmP = (float*)(ws + 18874368);  // 16K floats
    ushort* AO  = ws + 20971520;            // 4M (NOT aliased with Qp)

    const int tid = threadIdx.x;
    const int bid = blockIdx.x;
    const int lane = tid & 63, w = tid >> 6;
    const int c = lane & 15, g = lane >> 4;

    // ======================= Phase 0: converts =============================
#pragma unroll
    for (int i = 0; i < 10; ++i) {
        size_t off = (size_t)(i * 256 + bid) * 4096 + tid * 8;
        const float* src; size_t base;
        if (off < 4194304)      { src = tqF; base = 0; }
        else if (off < 6291456) { src = kvF; base = 4194304; }
        else if (off < 7340032) { src = wqF; base = 6291456; }
        else if (off < 8388608) { src = wkF; base = 7340032; }
        else if (off < 9437184) { src = wvF; base = 8388608; }
        else                    { src = woF; base = 9437184; }
        const float* s = src + (off - base);
        float4 a = *(const float4*)s;
        float4 b = *(const float4*)(s + 4);
        uint4 o;
        o.x = pk2(a.x, a.y); o.y = pk2(a.z, a.w);
        o.z = pk2(b.x, b.y); o.w = pk2(b.z, b.w);
        *(uint4*)(ws + off) = o;
    }
    __threadfence();
    grid.sync();

    // ======================= Phase 1: QKV GEMMs (2 tiles/WG) ===============
    for (int uu = 0; uu < 2; ++uu) {
        __syncthreads();
        ushort* Xs = smem;
        ushort* WsL = smem + 8192;

        int idx = bid + uu * 256;
        const ushort* X; const ushort* W; ushort* Yp; int kind; float scale = 1.f;
        int bm, bn;
        if (idx < 256)      { X = qx;  W = wq; Yp = Qp;  kind = 0; scale = SC2;
                              bm = (idx >> 3) * 128; bn = (idx & 7) * 128; }
        else if (idx < 384) { int j = idx - 256; X = kvx; W = wk; Yp = Kp; kind = 0;
                              bm = (j >> 3) * 128; bn = (j & 7) * 128; }
        else                { int j = idx - 384; X = kvx; W = wv; Yp = VtG; kind = 2;
                              bm = (j >> 3) * 128; bn = (j & 7) * 128; }

        const int wy = w >> 1, wx = w & 1;
        f32x4 acc[2][4] = {};

        for (int kt = 0; kt < 16; ++kt) {
            const int k0 = kt * 64;
#pragma unroll
            for (int j = 0; j < 2; ++j) {
                int u = w * 128 + j * 64 + lane;
                int row = u >> 3, gs = (u & 7) ^ (row & 7);
                gload16(Xs + (w * 128 + j * 64) * 8, X + (size_t)(bm + row) * K_ + k0 + gs * 8);
                gload16(WsL + (w * 128 + j * 64) * 8, W + (size_t)(bn + row) * K_ + k0 + gs * 8);
            }
            __syncthreads();
#pragma unroll
            for (int ks = 0; ks < 2; ++ks) {
                bf16x8 af[2], bfr[4];
#pragma unroll
                for (int mi = 0; mi < 2; ++mi) {
                    int row = wy * 32 + mi * 16 + c;
                    int s = ks * 4 + g;
                    af[mi] = *(const bf16x8*)(Xs + (row * 8 + (s ^ (row & 7))) * 8);
                }
#pragma unroll
                for (int ni = 0; ni < 4; ++ni) {
                    int row = wx * 64 + ni * 16 + c;
                    int s = ks * 4 + g;
                    bfr[ni] = *(const bf16x8*)(WsL + (row * 8 + (s ^ (row & 7))) * 8);
                }
#pragma unroll
                for (int mi = 0; mi < 2; ++mi)
#pragma unroll
                    for (int ni = 0; ni < 4; ++ni)
                        acc[mi][ni] = __builtin_amdgcn_mfma_f32_16x16x32_bf16(af[mi], bfr[ni], acc[mi][ni], 0, 0, 0);
            }
            __syncthreads();
        }

        if (kind == 0) {
#pragma unroll
            for (int mi = 0; mi < 2; ++mi)
#pragma unroll
                for (int ni = 0; ni < 4; ++ni)
#pragma unroll
                    for (int r = 0; r < 4; ++r) {
                        int row = bm + wy * 32 + mi * 16 + g * 4 + r;
                        int col = bn + wx * 64 + ni * 16 + c;
                        Yp[(size_t)row * 1024 + col] = f2bf(acc[mi][ni][r] * scale);
                    }
        } else {
            ushort* T = smem;                   // [128][136]
#pragma unroll
            for (int mi = 0; mi < 2; ++mi)
#pragma unroll
                for (int ni = 0; ni < 4; ++ni) {
                    ushort4 v4;
                    v4.x = f2bf(acc[mi][ni][0]); v4.y = f2bf(acc[mi][ni][1]);
                    v4.z = f2bf(acc[mi][ni][2]); v4.w = f2bf(acc[mi][ni][3]);
                    *(ushort4*)&T[(wx * 64 + ni * 16 + c) * 136 + wy * 32 + mi * 16 + g * 4] = v4;
                }
            __syncthreads();
            int b = bm >> 10;
            int rid = tid >> 2, quad = tid & 3;
            int n_c = bn + rid;
            int h = n_c >> 6, d = n_c & 63;
            int m0 = quad * 32;
            ushort* dst = Yp + (size_t)((b * NH_ + h) * 64 + d) * N_ + (bm & (N_ - 1)) + m0;
            float vsum = 0.f;
#pragma unroll
            for (int jj = 0; jj < 4; ++jj) {
                uint4 tt = *(const uint4*)&T[rid * 136 + m0 + jj * 8];
                *(uint4*)(dst + jj * 8) = tt;
                uint uw[4] = {tt.x, tt.y, tt.z, tt.w};
#pragma unroll
                for (int q2 = 0; q2 < 4; ++q2) {
                    vsum += __uint_as_float(uw[q2] << 16);
                    vsum += __uint_as_float(uw[q2] & 0xffff0000u);
                }
            }
            vsum += __shfl_xor(vsum, 1);
            vsum += __shfl_xor(vsum, 2);
            if (quad == 0) VmP[(bm >> 7) * 1024 + n_c] = vsum;   // race-free slot
        }
    }
    __threadfence();
    grid.sync();

    // ======================= Phase 2: attention (2 blocks/WG) ==============
    // WG pairs query-block indices j = m and 15-m (m = bid>>5) so per-WG
    // total tile count ~ constant (1 WG/CU load balance).
    for (int uu = 0; uu < 2; ++uu) {
        __syncthreads();
        ushort* Qs = smem;                     // 8192 (128x64)
        ushort* Ks = smem + 8192;              // 4096 (64x64)
        ushort* Vs = smem + 12288;             // 4096 (64x64 Vt)
        ushort* Ps = smem + 16384;             // 128x72 = 9216
        int* cntS  = (int*)(smem + 25600);     // 128 ints

        const int m = bid >> 5, k2 = bid & 31;
        const int j = (uu == 0) ? m : 15 - m;
        const int b = k2 & 1, h = k2 >> 1;
        const int t0 = j << 7;

        // stage Q (128 q x 64 d), 2 units/lane
#pragma unroll
        for (int jj = 0; jj < 2; ++jj) {
            int u = w * 128 + jj * 64 + lane;
            int row = u >> 3, gs = (u & 7) ^ (row & 7);
            gload16(Qs + (w * 128 + jj * 64) * 8,
                    Qp + (size_t)(b * S_ + t0 + row) * H_ + h * 64 + gs * 8);
        }
        if (tid < 128) {
            int t = t0 + tid;
            int lo = 0, hi = N_;
            while (lo < hi) { int mid = (lo + hi) >> 1; if (ends[mid] <= t) lo = mid + 1; else hi = mid; }
            cntS[tid] = lo;
        }

        const int u0 = w * 64 + lane, row0 = u0 >> 3, gs0 = (u0 & 7) ^ (row0 & 7);
        const ushort* kp0 = Kp + (size_t)(b * N_ + row0) * H_ + h * 64 + gs0 * 8;
        const ushort* vp0 = VtG + (size_t)((b * NH_ + h) * 64 + row0) * N_ + gs0 * 8;

        float l0 = 0.f;
        f32x4 o0[4] = {};

        __syncthreads();
        const int cntv = cntS[w * 16 + c];
        const int cnt_min = cntS[0];
        const int ntmax = (cntS[127] + 63) >> 6;

        bf16x8 bq[2];
#pragma unroll
        for (int ks = 0; ks < 2; ++ks) {
            int ra = w * 16 + c;
            int s = ks * 4 + g;
            bq[ks] = *(const bf16x8*)(Qs + (ra * 8 + (s ^ (ra & 7))) * 8);
        }

        for (int nt = 0; nt < ntmax; ++nt) {
            gload16(Ks + w * 512, kp0 + (size_t)nt * 64 * H_);
            gload16(Vs + w * 512, vp0 + nt * 64);
            __syncthreads();

            f32x4 st[4] = {};
#pragma unroll
            for (int ntile = 0; ntile < 4; ++ntile)
#pragma unroll
                for (int ks = 0; ks < 2; ++ks) {
                    int row = ntile * 16 + c;
                    int s = ks * 4 + g;
                    bf16x8 ak = *(const bf16x8*)(Ks + (row * 8 + (s ^ (row & 7))) * 8);
                    st[ntile] = __builtin_amdgcn_mfma_f32_16x16x32_bf16(ak, bq[ks], st[ntile], 0, 0, 0);
                }

            const bool full = ((nt + 1) << 6) <= cnt_min;
            float lsum = 0.f;
            ushort* prow = Ps + (size_t)(w * 16 + c) * 72;
            if (full) {
#pragma unroll
                for (int ntile = 0; ntile < 4; ++ntile) {
                    float a0 = fexp2(st[ntile][0]), a1 = fexp2(st[ntile][1]);
                    float a2 = fexp2(st[ntile][2]), a3 = fexp2(st[ntile][3]);
                    lsum += (a0 + a1) + (a2 + a3);
                    uint2 pw; pw.x = pk2(a0, a1); pw.y = pk2(a2, a3);
                    *(uint2*)(prow + ntile * 16 + g * 4) = pw;
                }
            } else {
                const int base = (nt << 6) + g * 4 - cntv;
#pragma unroll
                for (int ntile = 0; ntile < 4; ++ntile) {
                    float a0 = (base + ntile * 16 + 0 >= 0) ? 0.f : fexp2(st[ntile][0]);
                    float a1 = (base + ntile * 16 + 1 >= 0) ? 0.f : fexp2(st[ntile][1]);
                    float a2 = (base + ntile * 16 + 2 >= 0) ? 0.f : fexp2(st[ntile][2]);
                    float a3 = (base + ntile * 16 + 3 >= 0) ? 0.f : fexp2(st[ntile][3]);
                    lsum += (a0 + a1) + (a2 + a3);
                    uint2 pw; pw.x = pk2(a0, a1); pw.y = pk2(a2, a3);
                    *(uint2*)(prow + ntile * 16 + g * 4) = pw;
                }
            }
            lsum += __shfl_xor(lsum, 16);
            lsum += __shfl_xor(lsum, 32);
            l0 += lsum;

            bf16x8 ap[2];
#pragma unroll
            for (int ks = 0; ks < 2; ++ks)
                ap[ks] = *(const bf16x8*)(prow + ks * 32 + g * 8);
#pragma unroll
            for (int dt = 0; dt < 4; ++dt)
#pragma unroll
                for (int ks = 0; ks < 2; ++ks) {
                    int row = dt * 16 + c;
                    int s = ks * 4 + g;
                    bf16x8 bv = *(const bf16x8*)(Vs + (row * 8 + (s ^ (row & 7))) * 8);
                    o0[dt] = __builtin_amdgcn_mfma_f32_16x16x32_bf16(ap[ks], bv, o0[dt], 0, 0, 0);
                }
            __syncthreads();
        }

        float invl = 1.f / l0;
        float lr[4]; int cq[4];
#pragma unroll
        for (int r = 0; r < 4; ++r) {
            lr[r] = __shfl(invl, g * 4 + r);
            cq[r] = cntS[w * 16 + g * 4 + r];
        }
#pragma unroll
        for (int dt = 0; dt < 4; ++dt)
#pragma unroll
            for (int r = 0; r < 4; ++r) {
                int q = t0 + w * 16 + g * 4 + r;
                float val = o0[dt][r] * lr[r];
                if (cq[r] == 0) {
                    float sm = 0.f;
#pragma unroll
                    for (int jj = 0; jj < 8; ++jj)
                        sm += VmP[(b * 8 + jj) * 1024 + h * 64 + dt * 16 + c];
                    val = sm * (1.f / 1024.f);
                }
                AO[(size_t)(b * S_ + q) * H_ + h * 64 + dt * 16 + c] = f2bf(val);
            }
    }
    __threadfence();
    grid.sync();

    // ======================= Phase 3: out projection (2 tiles/WG) ==========
    for (int uu = 0; uu < 2; ++uu) {
        __syncthreads();
        ushort* Xs = smem;                 // 64x64
        ushort* WsL = smem + 4096;         // 128x64

        int idx = bid + uu * 256;
        const int bm = (idx >> 3) * 64;
        const int bn = (idx & 7) * 128;
        const int wy = w >> 2, wx = w & 3;

        const int rx = tid >> 3,  sx = (tid & 7) ^ (rx & 7);
        const int uw1 = tid + 512;
        const int rw1 = uw1 >> 3, sw1 = (uw1 & 7) ^ (rw1 & 7);

        const ushort* xp  = AO + (size_t)(bm + rx) * K_ + sx * 8;
        const ushort* wp0 = wo + (size_t)(bn + rx) * K_ + sx * 8;
        const ushort* wp1 = wo + (size_t)(bn + rw1) * K_ + sw1 * 8;

        f32x4 acc[2][2] = {};

        for (int kt = 0; kt < 16; ++kt) {
            const int k0 = kt * 64;
            gload16(Xs + (w * 64) * 8, xp + k0);
            gload16(WsL + (w * 64) * 8, wp0 + k0);
            gload16(WsL + (512 + w * 64) * 8, wp1 + k0);
            __syncthreads();
#pragma unroll
            for (int ks = 0; ks < 2; ++ks) {
                bf16x8 af[2], bfr[2];
                int s = ks * 4 + g;
#pragma unroll
                for (int mi = 0; mi < 2; ++mi) {
                    int row = wy * 32 + mi * 16 + c;
                    af[mi] = *(const bf16x8*)(Xs + (row * 8 + (s ^ (row & 7))) * 8);
                }
#pragma unroll
                for (int ni = 0; ni < 2; ++ni) {
                    int row = wx * 32 + ni * 16 + c;
                    bfr[ni] = *(const bf16x8*)(WsL + (row * 8 + (s ^ (row & 7))) * 8);
                }
#pragma unroll
                for (int mi = 0; mi < 2; ++mi)
#pragma unroll
                    for (int ni = 0; ni < 2; ++ni)
                        acc[mi][ni] = __builtin_amdgcn_mfma_f32_16x16x32_bf16(af[mi], bfr[ni], acc[mi][ni], 0, 0, 0);
            }
            __syncthreads();
        }

#pragma unroll
        for (int mi = 0; mi < 2; ++mi)
#pragma unroll
            for (int ni = 0; ni < 2; ++ni)
#pragma unroll
                for (int r = 0; r < 4; ++r) {
                    int row = bm + wy * 32 + mi * 16 + g * 4 + r;
                    int col = bn + wx * 32 + ni * 16 + c;
                    out[(size_t)row * 1024 + col] = acc[mi][ni][r];
                }
    }
}

// ===========================================================================
// Fallback path: the proven R7 four-kernel pipeline (verbatim).
// ===========================================================================
__global__ __launch_bounds__(256) void prep_kernel(const float* __restrict__ tq,
        const float* __restrict__ kv, const float* __restrict__ wq,
        const float* __restrict__ wk, const float* __restrict__ wv,
        const float* __restrict__ wo, ushort* __restrict__ dst)
{
    int blk = blockIdx.x;
    const float* src; size_t base;
    if (blk < 2048)      { src = tq; base = 0;       }
    else if (blk < 3072) { src = kv; base = 4194304; blk -= 2048; }
    else if (blk < 3584) { src = wq; base = 6291456; blk -= 3072; }
    else if (blk < 4096) { src = wk; base = 7340032; blk -= 3584; }
    else if (blk < 4608) { src = wv; base = 8388608; blk -= 4096; }
    else                 { src = wo; base = 9437184; blk -= 4608; }
    size_t i = (size_t)blk * 2048 + threadIdx.x * 8;
    float4 a = *(const float4*)(src + i);
    float4 b = *(const float4*)(src + i + 4);
    uint4 o;
    o.x = pk2(a.x, a.y); o.y = pk2(a.z, a.w);
    o.z = pk2(b.x, b.y); o.w = pk2(b.z, b.w);
    *(uint4*)(dst + base + i) = o;
}

__global__ __launch_bounds__(512) void gemm_qkv(
        const ushort* __restrict__ qx, const ushort* __restrict__ kvx,
        const ushort* __restrict__ wq, const ushort* __restrict__ wk,
        const ushort* __restrict__ wv,
        ushort* __restrict__ Qp, ushort* __restrict__ Kp,
        ushort* __restrict__ VtG, float* __restrict__ VmP)
{
    __shared__ __align__(16) ushort smem[17408];
    ushort* Xs = smem;
    ushort* Ws = smem + 8192;

    const ushort* X; const ushort* W; void* Yp; int kind; float scale = 1.f;
    int bm, bn;
    {
        int idx = blockIdx.x;
        if (idx < 256)      { X = qx;  W = wq; Yp = Qp;  kind = 0; scale = SC2;
                              bm = (idx >> 3) * 128; bn = (idx & 7) * 128; }
        else if (idx < 384) { int j = idx - 256; X = kvx; W = wk; Yp = Kp; kind = 0;
                              bm = (j >> 3) * 128; bn = (j & 7) * 128; }
        else                { int j = idx - 384; X = kvx; W = wv; Yp = VtG; kind = 2;
                              bm = (j >> 3) * 128; bn = (j & 7) * 128; }
    }

    const int tid = threadIdx.x;
    const int lane = tid & 63, w = tid >> 6;
    const int wy = w >> 1, wx = w & 1;
    const int c = lane & 15, g = lane >> 4;

    f32x4 acc[2][4] = {};

    for (int kt = 0; kt < 16; ++kt) {
        const int k0 = kt * 64;
#pragma unroll
        for (int j = 0; j < 2; ++j) {
            int u = w * 128 + j * 64 + lane;
            int row = u >> 3, gs = (u & 7) ^ (row & 7);
            gload16(Xs + (w * 128 + j * 64) * 8, X + (size_t)(bm + row) * K_ + k0 + gs * 8);
            gload16(Ws + (w * 128 + j * 64) * 8, W + (size_t)(bn + row) * K_ + k0 + gs * 8);
        }
        __syncthreads();
#pragma unroll
        for (int ks = 0; ks < 2; ++ks) {
            bf16x8 af[2], bfr[4];
#pragma unroll
            for (int mi = 0; mi < 2; ++mi) {
                int row = wy * 32 + mi * 16 + c;
                int s = ks * 4 + g;
                af[mi] = *(const bf16x8*)(Xs + (row * 8 + (s ^ (row & 7))) * 8);
            }
#pragma unroll
            for (int ni = 0; ni < 4; ++ni) {
                int row = wx * 64 + ni * 16 + c;
                int s = ks * 4 + g;
                bfr[ni] = *(const bf16x8*)(Ws + (row * 8 + (s ^ (row & 7))) * 8);
            }
#pragma unroll
            for (int mi = 0; mi < 2; ++mi)
#pragma unroll
                for (int ni = 0; ni < 4; ++ni)
                    acc[mi][ni] = __builtin_amdgcn_mfma_f32_16x16x32_bf16(af[mi], bfr[ni], acc[mi][ni], 0, 0, 0);
        }
        __syncthreads();
    }

    if (kind == 0) {
        ushort* Y = (ushort*)Yp;
#pragma unroll
        for (int mi = 0; mi < 2; ++mi)
#pragma unroll
            for (int ni = 0; ni < 4; ++ni)
#pragma unroll
                for (int r = 0; r < 4; ++r) {
                    int row = bm + wy * 32 + mi * 16 + g * 4 + r;
                    int col = bn + wx * 64 + ni * 16 + c;
                    Y[(size_t)row * 1024 + col] = f2bf(acc[mi][ni][r] * scale);
                }
    } else {
        ushort* T = smem;
#pragma unroll
        for (int mi = 0; mi < 2; ++mi)
#pragma unroll
            for (int ni = 0; ni < 4; ++ni) {
                ushort4 v4;
                v4.x = f2bf(acc[mi][ni][0]); v4.y = f2bf(acc[mi][ni][1]);
                v4.z = f2bf(acc[mi][ni][2]); v4.w = f2bf(acc[mi][ni][3]);
                *(ushort4*)&T[(wx * 64 + ni * 16 + c) * 136 + wy * 32 + mi * 16 + g * 4] = v4;
            }
        __syncthreads();
        ushort* Vt = (ushort*)Yp;
        int b = bm >> 10;
        int rid = tid >> 2, quad = tid & 3;
        int n_c = bn + rid;
        int h = n_c >> 6, d = n_c & 63;
        int m0 = quad * 32;
        ushort* dst = Vt + (size_t)((b * NH_ + h) * 64 + d) * N_ + (bm & (N_ - 1)) + m0;
        float vsum = 0.f;
#pragma unroll
        for (int jj = 0; jj < 4; ++jj) {
            uint4 tt = *(const uint4*)&T[rid * 136 + m0 + jj * 8];
            *(uint4*)(dst + jj * 8) = tt;
            uint uw[4] = {tt.x, tt.y, tt.z, tt.w};
#pragma unroll
            for (int q2 = 0; q2 < 4; ++q2) {
                vsum += __uint_as_float(uw[q2] << 16);
                vsum += __uint_as_float(uw[q2] & 0xffff0000u);
            }
        }
        vsum += __shfl_xor(vsum, 1);
        vsum += __shfl_xor(vsum, 2);
        if (quad == 0) VmP[(bm >> 7) * 1024 + n_c] = vsum;
    }
}

__global__ __launch_bounds__(256) void attn_mfma(const ushort* __restrict__ Qp,
                                                 const ushort* __restrict__ Kp,
                                                 const ushort* __restrict__ VtG,
                                                 const int* __restrict__ ends,
                                                 const float* __restrict__ VmP,
                                                 ushort* __restrict__ AO)
{
    __shared__ __align__(16) ushort Qs[128 * 64];
    __shared__ __align__(16) ushort Ks[64 * 64];
    __shared__ __align__(16) ushort Vs[64 * 64];
    __shared__ __align__(16) ushort Ps[128][72];
    __shared__ int cntS[128];

    const int id = blockIdx.x;
    const int b = id & 1, h = (id >> 1) & 15;
    const int tb = id >> 5;
    const int t0 = (tb < 8 ? tb : 23 - tb) << 7;
    const int tid = threadIdx.x, lane = tid & 63, w = tid >> 6;
    const int c = lane & 15, g = lane >> 4;

#pragma unroll
    for (int jj = 0; jj < 4; ++jj) {
        int u = w * 256 + jj * 64 + lane;
        int row = u >> 3, gs = (u & 7) ^ (row & 7);
        gload16(Qs + (w * 256 + jj * 64) * 8,
                Qp + (size_t)(b * S_ + t0 + row) * H_ + h * 64 + gs * 8);
    }
    if (tid < 128) {
        int t = t0 + tid;
        int lo = 0, hi = N_;
        while (lo < hi) { int mid = (lo + hi) >> 1; if (ends[mid] <= t) lo = mid + 1; else hi = mid; }
        cntS[tid] = lo;
    }

    const int u0 = (w * 2) * 64 + lane, row0 = u0 >> 3, gs0 = (u0 & 7) ^ (row0 & 7);
    const int u1 = (w * 2 + 1) * 64 + lane, row1 = u1 >> 3, gs1 = (u1 & 7) ^ (row1 & 7);
    const ushort* kp0 = Kp + (size_t)(b * N_ + row0) * H_ + h * 64 + gs0 * 8;
    const ushort* kp1 = Kp + (size_t)(b * N_ + row1) * H_ + h * 64 + gs1 * 8;
    const ushort* vp0 = VtG + (size_t)((b * NH_ + h) * 64 + row0) * N_ + gs0 * 8;
    const ushort* vp1 = VtG + (size_t)((b * NH_ + h) * 64 + row1) * N_ + gs1 * 8;

    float l0 = 0.f, l1 = 0.f;
    f32x4 o0[4] = {}, o1[4] = {};

    __syncthreads();
    const int cntv0 = cntS[w * 32 + c];
    const int cntv1 = cntS[w * 32 + 16 + c];
    const int cnt_min = cntS[0];
    const int ntmax = (cntS[127] + 63) >> 6;

    bf16x8 bq0[2], bq1[2];
#pragma unroll
    for (int ks = 0; ks < 2; ++ks) {
        int s = ks * 4 + g;
        int ra = w * 32 + c;
        bq0[ks] = *(const bf16x8*)(Qs + (ra * 8 + (s ^ (ra & 7))) * 8);
        int rb = w * 32 + 16 + c;
        bq1[ks] = *(const bf16x8*)(Qs + (rb * 8 + (s ^ (rb & 7))) * 8);
    }

    for (int nt = 0; nt < ntmax; ++nt) {
        gload16(Ks + (w * 2) * 512, kp0 + (size_t)nt * 64 * H_);
        gload16(Ks + (w * 2 + 1) * 512, kp1 + (size_t)nt * 64 * H_);
        gload16(Vs + (w * 2) * 512, vp0 + nt * 64);
        gload16(Vs + (w * 2 + 1) * 512, vp1 + nt * 64);
        __syncthreads();

        f32x4 st0[4] = {}, st1[4] = {};
#pragma unroll
        for (int ntile = 0; ntile < 4; ++ntile)
#pragma unroll
            for (int ks = 0; ks < 2; ++ks) {
                int row = ntile * 16 + c;
                int s = ks * 4 + g;
                bf16x8 ak = *(const bf16x8*)(Ks + (row * 8 + (s ^ (row & 7))) * 8);
                st0[ntile] = __builtin_amdgcn_mfma_f32_16x16x32_bf16(ak, bq0[ks], st0[ntile], 0, 0, 0);
                st1[ntile] = __builtin_amdgcn_mfma_f32_16x16x32_bf16(ak, bq1[ks], st1[ntile], 0, 0, 0);
            }

        const bool full = ((nt + 1) << 6) <= cnt_min;
        float lsum0 = 0.f, lsum1 = 0.f;
        if (full) {
#pragma unroll
            for (int ntile = 0; ntile < 4; ++ntile) {
                float a0 = fexp2(st0[ntile][0]), a1 = fexp2(st0[ntile][1]);
                float a2 = fexp2(st0[ntile][2]), a3 = fexp2(st0[ntile][3]);
                lsum0 += (a0 + a1) + (a2 + a3);
                uint2 pw; pw.x = pk2(a0, a1); pw.y = pk2(a2, a3);
                *(uint2*)&Ps[w * 32 + c][ntile * 16 + g * 4] = pw;
                float b0 = fexp2(st1[ntile][0]), b1 = fexp2(st1[ntile][1]);
                float b2 = fexp2(st1[ntile][2]), b3 = fexp2(st1[ntile][3]);
                lsum1 += (b0 + b1) + (b2 + b3);
                uint2 qw; qw.x = pk2(b0, b1); qw.y = pk2(b2, b3);
                *(uint2*)&Ps[w * 32 + 16 + c][ntile * 16 + g * 4] = qw;
            }
        } else {
            const int base0 = (nt << 6) + g * 4 - cntv0;
            const int base1 = (nt << 6) + g * 4 - cntv1;
#pragma unroll
            for (int ntile = 0; ntile < 4; ++ntile) {
                float a0 = (base0 + ntile * 16 + 0 >= 0) ? 0.f : fexp2(st0[ntile][0]);
                float a1 = (base0 + ntile * 16 + 1 >= 0) ? 0.f : fexp2(st0[ntile][1]);
                float a2 = (base0 + ntile * 16 + 2 >= 0) ? 0.f : fexp2(st0[ntile][2]);
                float a3 = (base0 + ntile * 16 + 3 >= 0) ? 0.f : fexp2(st0[ntile][3]);
                lsum0 += (a0 + a1) + (a2 + a3);
                uint2 pw; pw.x = pk2(a0, a1); pw.y = pk2(a2, a3);
                *(uint2*)&Ps[w * 32 + c][ntile * 16 + g * 4] = pw;
                float b0 = (base1 + ntile * 16 + 0 >= 0) ? 0.f : fexp2(st1[ntile][0]);
                float b1 = (base1 + ntile * 16 + 1 >= 0) ? 0.f : fexp2(st1[ntile][1]);
                float b2 = (base1 + ntile * 16 + 2 >= 0) ? 0.f : fexp2(st1[ntile][2]);
                float b3 = (base1 + ntile * 16 + 3 >= 0) ? 0.f : fexp2(st1[ntile][3]);
                lsum1 += (b0 + b1) + (b2 + b3);
                uint2 qw; qw.x = pk2(b0, b1); qw.y = pk2(b2, b3);
                *(uint2*)&Ps[w * 32 + 16 + c][ntile * 16 + g * 4] = qw;
            }
        }
        lsum0 += __shfl_xor(lsum0, 16); lsum0 += __shfl_xor(lsum0, 32);
        lsum1 += __shfl_xor(lsum1, 16); lsum1 += __shfl_xor(lsum1, 32);
        l0 += lsum0; l1 += lsum1;

        bf16x8 ap0[2], ap1[2];
#pragma unroll
        for (int ks = 0; ks < 2; ++ks) {
            ap0[ks] = *(const bf16x8*)&Ps[w * 32 + c][ks * 32 + g * 8];
            ap1[ks] = *(const bf16x8*)&Ps[w * 32 + 16 + c][ks * 32 + g * 8];
        }
#pragma unroll
        for (int dt = 0; dt < 4; ++dt)
#pragma unroll
            for (int ks = 0; ks < 2; ++ks) {
                int row = dt * 16 + c;
                int s = ks * 4 + g;
                bf16x8 bv = *(const bf16x8*)(Vs + (row * 8 + (s ^ (row & 7))) * 8);
                o0[dt] = __builtin_amdgcn_mfma_f32_16x16x32_bf16(ap0[ks], bv, o0[dt], 0, 0, 0);
                o1[dt] = __builtin_amdgcn_mfma_f32_16x16x32_bf16(ap1[ks], bv, o1[dt], 0, 0, 0);
            }
        __syncthreads();
    }

#pragma unroll
    for (int qt = 0; qt < 2; ++qt) {
        float invl = 1.f / (qt == 0 ? l0 : l1);
        f32x4* o = (qt == 0 ? o0 : o1);
        float lr[4]; int cq[4];
#pragma unroll
        for (int r = 0; r < 4; ++r) {
            lr[r] = __shfl(invl, g * 4 + r);
            cq[r] = cntS[w * 32 + qt * 16 + g * 4 + r];
        }
#pragma unroll
        for (int dt = 0; dt < 4; ++dt)
#pragma unroll
            for (int r = 0; r < 4; ++r) {
                int q = t0 + w * 32 + qt * 16 + g * 4 + r;
                float val = o[dt][r] * lr[r];
                if (cq[r] == 0) {
                    float sm = 0.f;
#pragma unroll
                    for (int j = 0; j < 8; ++j)
                        sm += VmP[(b * 8 + j) * 1024 + h * 64 + dt * 16 + c];
                    val = sm * (1.f / 1024.f);
                }
                AO[(size_t)(b * S_ + q) * H_ + h * 64 + dt * 16 + c] = f2bf(val);
            }
    }
}

__global__ __launch_bounds__(512) void gemm_out(const ushort* __restrict__ AO,
                                                const ushort* __restrict__ wo,
                                                float* __restrict__ out)
{
    __shared__ __align__(16) ushort Xs[64 * 64];
    __shared__ __align__(16) ushort Ws[128 * 64];

    const int bm = (blockIdx.x >> 3) * 64;
    const int bn = (blockIdx.x & 7) * 128;
    const int tid = threadIdx.x, lane = tid & 63, w = tid >> 6;
    const int wy = w >> 2, wx = w & 3;
    const int c = lane & 15, g = lane >> 4;

    const int rx = tid >> 3,  sx = (tid & 7) ^ (rx & 7);
    const int uw1 = tid + 512;
    const int rw1 = uw1 >> 3, sw1 = (uw1 & 7) ^ (rw1 & 7);

    const ushort* xp  = AO + (size_t)(bm + rx) * K_ + sx * 8;
    const ushort* wp0 = wo + (size_t)(bn + rx) * K_ + sx * 8;
    const ushort* wp1 = wo + (size_t)(bn + rw1) * K_ + sw1 * 8;

    f32x4 acc[2][2] = {};

    for (int kt = 0; kt < 16; ++kt) {
        const int k0 = kt * 64;
        gload16(Xs + (w * 64) * 8, xp + k0);
        gload16(Ws + (w * 64) * 8, wp0 + k0);
        gload16(Ws + (512 + w * 64) * 8, wp1 + k0);
        __syncthreads();
#pragma unroll
        for (int ks = 0; ks < 2; ++ks) {
            bf16x8 af[2], bfr[2];
            int s = ks * 4 + g;
#pragma unroll
            for (int mi = 0; mi < 2; ++mi) {
                int row = wy * 32 + mi * 16 + c;
                af[mi] = *(const bf16x8*)(Xs + (row * 8 + (s ^ (row & 7))) * 8);
            }
#pragma unroll
            for (int ni = 0; ni < 2; ++ni) {
                int row = wx * 32 + ni * 16 + c;
                bfr[ni] = *(const bf16x8*)(Ws + (row * 8 + (s ^ (row & 7))) * 8);
            }
#pragma unroll
            for (int mi = 0; mi < 2; ++mi)
#pragma unroll
                for (int ni = 0; ni < 2; ++ni)
                    acc[mi][ni] = __builtin_amdgcn_mfma_f32_16x16x32_bf16(af[mi], bfr[ni], acc[mi][ni], 0, 0, 0);
        }
        __syncthreads();
    }

#pragma unroll
    for (int mi = 0; mi < 2; ++mi)
#pragma unroll
        for (int ni = 0; ni < 2; ++ni)
#pragma unroll
            for (int r = 0; r < 4; ++r) {
                int row = bm + wy * 32 + mi * 16 + g * 4 + r;
                int col = bn + wx * 32 + ni * 16 + c;
                out[(size_t)row * 1024 + col] = acc[mi][ni][r];
            }
}

// ---------------------------------------------------------------------------
extern "C" void kernel_launch(void* const* d_in, const int* in_sizes, int n_in,
                              void* d_out, int out_size, void* d_ws, size_t ws_size,
                              hipStream_t stream) {
    const float* token_q    = (const float*)d_in[0];
    const float* block_kv   = (const float*)d_in[1];
    const int*   block_ends = (const int*)d_in[2];
    const float* Wq = (const float*)d_in[3];
    const float* Wk = (const float*)d_in[4];
    const float* Wv = (const float*)d_in[5];
    const float* Wo = (const float*)d_in[6];
    float* out = (float*)d_out;
    ushort* ws = (ushort*)d_ws;

    void* args[] = {
        (void*)&token_q, (void*)&block_kv,
        (void*)&Wq, (void*)&Wk, (void*)&Wv, (void*)&Wo,
        (void*)&block_ends, (void*)&ws, (void*)&out
    };
    hipError_t err = hipLaunchCooperativeKernel((const void*)mega, dim3(256),
                                                dim3(512), args, 0, stream);
    if (err != hipSuccess) {
        // Fallback: proven 4-kernel pipeline (R7, 159 us)
        ushort* qx  = ws;
        ushort* kvx = ws + (size_t)4 * 1024 * 1024;
        ushort* wqb = ws + (size_t)6 * 1024 * 1024;
        ushort* wkb = ws + (size_t)7 * 1024 * 1024;
        ushort* wvb = ws + (size_t)8 * 1024 * 1024;
        ushort* wob = ws + (size_t)9 * 1024 * 1024;
        ushort* Qp  = ws + (size_t)10 * 1024 * 1024;
        ushort* Kp  = ws + (size_t)14 * 1024 * 1024;
        ushort* VtG = ws + (size_t)16 * 1024 * 1024;
        float*  VmP = (float*)(ws + (size_t)18 * 1024 * 1024);

        prep_kernel<<<5120, 256, 0, stream>>>(token_q, block_kv, Wq, Wk, Wv, Wo, ws);
        gemm_qkv<<<512, 512, 0, stream>>>(qx, kvx, wqb, wkb, wvb, Qp, Kp, VtG, VmP);
        attn_mfma<<<512, 256, 0, stream>>>(Qp, Kp, VtG, block_ends, VmP, Qp);
        gemm_out<<<512, 512, 0, stream>>>(Qp, wob, out);
    }
}